// Round 1
// baseline (944.783 us; speedup 1.0000x reference)
//
#include <hip/hip_runtime.h>
#include <hip/hip_bf16.h>

// MultiDilatelocalAttention: fp32 baseline.
// x:[16,56,56,384] -> qkv = x @ w_qkv^T : [50176, 1152] (ws)
// -> 3-dilation local attention (k=3, dil=1,2,3; 4 heads x d=32 per branch) -> y:[50176,384] (ws)
// -> out = y @ w_proj^T + b_proj : [50176, 384] (d_out)

#define NTOK 50176
#define ROWQKV 1152
#define CDIM 384

// ---------------- Tiled fp32 GEMM: C[M][N] = A[M][K] * B[N][K]^T (+bias) ----------------
// TM=TN=128, TK=16, 256 threads, 8x8 acc per thread.
__global__ __launch_bounds__(256) void gemm_nt(const float* __restrict__ A,
                                               const float* __restrict__ B,
                                               const float* __restrict__ bias,
                                               float* __restrict__ C,
                                               int M, int N, int K) {
  __shared__ float As[16][136];  // transposed: As[k][row], stride 136 (16B-aligned rows)
  __shared__ float Bs[16][136];
  const int tid = threadIdx.x;
  const int tx = tid & 15, ty = tid >> 4;
  const size_t row0 = (size_t)blockIdx.x * 128;
  const int col0 = blockIdx.y * 128;

  float acc[8][8];
#pragma unroll
  for (int i = 0; i < 8; ++i)
#pragma unroll
    for (int j = 0; j < 8; ++j) acc[i][j] = 0.f;

  // loader: 128 rows x 16 k floats per tile; thread -> (row = tid/4, k4 = (tid%4)*4), 2 row-halves
  const int lrow = tid >> 2;        // 0..63
  const int lk4 = (tid & 3) * 4;    // 0,4,8,12
  const float* Aptr = A + (row0 + lrow) * (size_t)K + lk4;
  const float* Bptr = B + ((size_t)(col0 + lrow)) * (size_t)K + lk4;

  for (int k0 = 0; k0 < K; k0 += 16) {
    float4 a0 = *(const float4*)(Aptr + k0);
    float4 a1 = *(const float4*)(Aptr + (size_t)64 * K + k0);
    float4 b0 = *(const float4*)(Bptr + k0);
    float4 b1 = *(const float4*)(Bptr + (size_t)64 * K + k0);
    __syncthreads();
    As[lk4 + 0][lrow] = a0.x; As[lk4 + 1][lrow] = a0.y;
    As[lk4 + 2][lrow] = a0.z; As[lk4 + 3][lrow] = a0.w;
    As[lk4 + 0][lrow + 64] = a1.x; As[lk4 + 1][lrow + 64] = a1.y;
    As[lk4 + 2][lrow + 64] = a1.z; As[lk4 + 3][lrow + 64] = a1.w;
    Bs[lk4 + 0][lrow] = b0.x; Bs[lk4 + 1][lrow] = b0.y;
    Bs[lk4 + 2][lrow] = b0.z; Bs[lk4 + 3][lrow] = b0.w;
    Bs[lk4 + 0][lrow + 64] = b1.x; Bs[lk4 + 1][lrow + 64] = b1.y;
    Bs[lk4 + 2][lrow + 64] = b1.z; Bs[lk4 + 3][lrow + 64] = b1.w;
    __syncthreads();
#pragma unroll
    for (int k = 0; k < 16; ++k) {
      float4 a0v = *(const float4*)&As[k][ty * 8];
      float4 a1v = *(const float4*)&As[k][ty * 8 + 4];
      float4 b0v = *(const float4*)&Bs[k][tx * 8];
      float4 b1v = *(const float4*)&Bs[k][tx * 8 + 4];
      float a[8] = {a0v.x, a0v.y, a0v.z, a0v.w, a1v.x, a1v.y, a1v.z, a1v.w};
      float b[8] = {b0v.x, b0v.y, b0v.z, b0v.w, b1v.x, b1v.y, b1v.z, b1v.w};
#pragma unroll
      for (int i = 0; i < 8; ++i)
#pragma unroll
        for (int j = 0; j < 8; ++j) acc[i][j] = fmaf(a[i], b[j], acc[i][j]);
    }
  }

#pragma unroll
  for (int i = 0; i < 8; ++i) {
    size_t r = row0 + ty * 8 + i;
    float* crow = C + r * (size_t)N + col0 + tx * 8;
    float bz[8];
#pragma unroll
    for (int j = 0; j < 8; ++j)
      bz[j] = acc[i][j] + (bias ? bias[col0 + tx * 8 + j] : 0.f);
    *(float4*)(crow) = make_float4(bz[0], bz[1], bz[2], bz[3]);
    *(float4*)(crow + 4) = make_float4(bz[4], bz[5], bz[6], bz[7]);
  }
}

// ---------------- Local attention: one wave per (token, branch) ----------------
// lane l in [0,64): channels c0 = branch*128 + l (heads 0,1), c1 = c0 + 64 (heads 2,3).
__global__ __launch_bounds__(256) void attn_kernel(const float* __restrict__ qkv,
                                                   float* __restrict__ y) {
  const int lane = threadIdx.x & 63;
  const int wv = threadIdx.x >> 6;
  const int token = blockIdx.x * 4 + wv;
  const int branch = blockIdx.y;
  const int dil = branch + 1;
  const int xx = token % 56;
  const int yy = (token / 56) % 56;
  const int bimg = token / 3136;
  const float scale = 0.17677669529663687f;  // 1/sqrt(32)
  const int cb = branch * 128;

  const float* qrow = qkv + (size_t)token * ROWQKV;
  const float q0 = qrow[cb + lane];
  const float q1 = qrow[cb + 64 + lane];

  float l0[9], l1[9], v0[9], v1[9];
#pragma unroll
  for (int j = 0; j < 9; ++j) {
    const int ny = yy + (j / 3 - 1) * dil;
    const int nx = xx + (j % 3 - 1) * dil;
    float k0 = 0.f, k1 = 0.f, vv0 = 0.f, vv1 = 0.f;
    if ((unsigned)ny < 56u && (unsigned)nx < 56u) {
      const float* nrow = qkv + ((size_t)(bimg * 3136 + ny * 56 + nx)) * ROWQKV;
      k0 = nrow[384 + cb + lane];
      k1 = nrow[384 + cb + 64 + lane];
      vv0 = nrow[768 + cb + lane];
      vv1 = nrow[768 + cb + 64 + lane];
    }
    float p0 = q0 * k0, p1 = q1 * k1;
#pragma unroll
    for (int s = 1; s < 32; s <<= 1) {
      p0 += __shfl_xor(p0, s, 64);
      p1 += __shfl_xor(p1, s, 64);
    }
    l0[j] = p0 * scale;
    l1[j] = p1 * scale;
    v0[j] = vv0;
    v1[j] = vv1;
  }

  // softmax over the 9 taps (zero-padded taps contribute logit 0, v 0 — matches reference)
  float m0 = l0[0], m1 = l1[0];
#pragma unroll
  for (int j = 1; j < 9; ++j) { m0 = fmaxf(m0, l0[j]); m1 = fmaxf(m1, l1[j]); }
  float s0 = 0.f, s1 = 0.f;
#pragma unroll
  for (int j = 0; j < 9; ++j) {
    l0[j] = expf(l0[j] - m0); s0 += l0[j];
    l1[j] = expf(l1[j] - m1); s1 += l1[j];
  }
  const float r0 = 1.f / s0, r1 = 1.f / s1;
  float o0 = 0.f, o1 = 0.f;
#pragma unroll
  for (int j = 0; j < 9; ++j) { o0 = fmaf(l0[j], v0[j], o0); o1 = fmaf(l1[j], v1[j], o1); }

  float* yrow = y + (size_t)token * CDIM + cb;
  yrow[lane] = o0 * r0;
  yrow[64 + lane] = o1 * r1;
}

extern "C" void kernel_launch(void* const* d_in, const int* in_sizes, int n_in,
                              void* d_out, int out_size, void* d_ws, size_t ws_size,
                              hipStream_t stream) {
  const float* x = (const float*)d_in[0];       // [16,56,56,384]
  const float* w_qkv = (const float*)d_in[1];   // [1152,384]
  const float* w_proj = (const float*)d_in[2];  // [384,384]
  const float* b_proj = (const float*)d_in[3];  // [384]
  float* out = (float*)d_out;                   // [50176,384]

  float* qkv = (float*)d_ws;                       // 50176*1152 fp32 = 231 MB
  float* y = qkv + (size_t)NTOK * ROWQKV;          // 50176*384 fp32 = 77 MB

  // 1) qkv = x @ w_qkv^T
  gemm_nt<<<dim3(NTOK / 128, ROWQKV / 128), 256, 0, stream>>>(
      x, w_qkv, nullptr, qkv, NTOK, ROWQKV, CDIM);

  // 2) multi-dilation local attention -> y
  attn_kernel<<<dim3(NTOK / 4, 3), 256, 0, stream>>>(qkv, y);

  // 3) out = y @ w_proj^T + b_proj
  gemm_nt<<<dim3(NTOK / 128, CDIM / 128), 256, 0, stream>>>(
      y, w_proj, b_proj, out, NTOK, CDIM, CDIM);
}

// Round 2
// 315.464 us; speedup vs baseline: 2.9949x; 2.9949x over previous
//
#include <hip/hip_runtime.h>
#include <hip/hip_bf16.h>

// MultiDilatelocalAttention, round 2: f16 MFMA GEMMs + fp16 intermediates.
// x[50176,384]f32 -> xh f16 -> qkv_h[50176,1152]f16 (MFMA gemm)
// -> 3-dilation local attn (fp32 math on f16 in/out) -> y_h[50176,384]f16
// -> out[50176,384]f32 = y_h @ w_proj^T + b_proj (MFMA gemm, f32 out).

#define NTOK 50176
#define ROWQKV 1152
#define CDIM 384

typedef _Float16 half8 __attribute__((ext_vector_type(8)));
typedef float floatx4 __attribute__((ext_vector_type(4)));

typedef __attribute__((address_space(1))) const unsigned int GU32;
typedef __attribute__((address_space(3))) unsigned int LU32;

// ---------------- fp32 -> fp16 conversion ----------------
__global__ __launch_bounds__(256) void conv_f32_f16(const float* __restrict__ in,
                                                    _Float16* __restrict__ out, int n4) {
  int i = blockIdx.x * 256 + threadIdx.x;
  const int stride = gridDim.x * 256;
  for (; i < n4; i += stride) {
    float4 v = ((const float4*)in)[i];
    union { _Float16 h[4]; uint2 u; } o;
    o.h[0] = (_Float16)v.x; o.h[1] = (_Float16)v.y;
    o.h[2] = (_Float16)v.z; o.h[3] = (_Float16)v.w;
    ((uint2*)out)[i] = o.u;
  }
}

// ---------------- f16 MFMA GEMM: C[M][N] = A[M][K] * B[N][K]^T ----------------
// 128x128 tile, BK=32, 256 threads (4 waves, 2x2), 4x4 frags of 16x16x32 per wave.
// LDS granule swizzle: 16B slot ^= (row>>1)&3 (applied to gload_lds SOURCE and ds_read).
template <bool HALF_OUT>
__global__ __launch_bounds__(256) void gemm_f16(const _Float16* __restrict__ A,
                                                const _Float16* __restrict__ B,
                                                const float* __restrict__ bias,
                                                void* __restrict__ Cout,
                                                int N, int K) {
  __shared__ _Float16 As[128 * 32];
  __shared__ _Float16 Bs[128 * 32];
  const int tid = threadIdx.x;
  const int lane = tid & 63;
  const int wv = tid >> 6;
  const int wr = wv >> 1, wc = wv & 1;
  const size_t row0 = (size_t)blockIdx.x * 128;
  const int col0 = blockIdx.y * 128;

  // staging: thread -> granule tid (row=tid>>2, slot=tid&3) and granule tid+256 (row+64, same slot)
  const int srow = tid >> 2;
  const int sslot = tid & 3;
  const int gslot = sslot ^ ((srow >> 1) & 3);  // swizzled source slot (same for row+64)
  const _Float16* Abase = A + (row0 + srow) * (size_t)K + gslot * 8;
  const _Float16* Bbase = B + ((size_t)(col0 + srow)) * (size_t)K + gslot * 8;
  char* AsB = (char*)As;
  char* BsB = (char*)Bs;

  // fragment read addressing
  const int fr = lane & 15;
  const int fq = lane >> 4;
  const int rpos = (fq ^ ((fr >> 1) & 3)) * 8;  // swizzled half-offset within row

  floatx4 acc[4][4];
#pragma unroll
  for (int i = 0; i < 4; ++i)
#pragma unroll
    for (int j = 0; j < 4; ++j) acc[i][j] = (floatx4){0.f, 0.f, 0.f, 0.f};

  for (int k0 = 0; k0 < K; k0 += 32) {
    __builtin_amdgcn_global_load_lds((GU32*)(Abase + k0), (LU32*)(AsB + tid * 16), 16, 0, 0);
    __builtin_amdgcn_global_load_lds((GU32*)(Abase + (size_t)64 * K + k0),
                                     (LU32*)(AsB + tid * 16 + 4096), 16, 0, 0);
    __builtin_amdgcn_global_load_lds((GU32*)(Bbase + k0), (LU32*)(BsB + tid * 16), 16, 0, 0);
    __builtin_amdgcn_global_load_lds((GU32*)(Bbase + (size_t)64 * K + k0),
                                     (LU32*)(BsB + tid * 16 + 4096), 16, 0, 0);
    __syncthreads();  // compiler drains vmcnt(0): tile ready
    half8 af[4], bf[4];
#pragma unroll
    for (int f = 0; f < 4; ++f) {
      af[f] = *(const half8*)&As[(wr * 64 + f * 16 + fr) * 32 + rpos];
      bf[f] = *(const half8*)&Bs[(wc * 64 + f * 16 + fr) * 32 + rpos];
    }
#pragma unroll
    for (int i = 0; i < 4; ++i)
#pragma unroll
      for (int j = 0; j < 4; ++j)
        acc[i][j] = __builtin_amdgcn_mfma_f32_16x16x32_f16(af[i], bf[j], acc[i][j], 0, 0, 0);
    __syncthreads();  // all waves done reading before restage
  }

  // epilogue: C/D layout col=lane&15, row=(lane>>4)*4+reg
  const int crow = wr * 64 + (lane >> 4) * 4;
  const int ccol = wc * 64 + (lane & 15);
#pragma unroll
  for (int fm = 0; fm < 4; ++fm) {
#pragma unroll
    for (int fn = 0; fn < 4; ++fn) {
      const size_t r0 = (row0 + crow + fm * 16) * (size_t)N + col0 + ccol + fn * 16;
      if (HALF_OUT) {
        _Float16* C = (_Float16*)Cout;
#pragma unroll
        for (int j = 0; j < 4; ++j) C[r0 + (size_t)j * N] = (_Float16)acc[fm][fn][j];
      } else {
        float* C = (float*)Cout;
        const float bz = bias[col0 + ccol + fn * 16];
#pragma unroll
        for (int j = 0; j < 4; ++j) C[r0 + (size_t)j * N] = acc[fm][fn][j] + bz;
      }
    }
  }
}

// ---------------- Local attention (fp16 in/out, fp32 math) ----------------
__global__ __launch_bounds__(256) void attn_kernel(const _Float16* __restrict__ qkv,
                                                   _Float16* __restrict__ y) {
  const int lane = threadIdx.x & 63;
  const int wv = threadIdx.x >> 6;
  const int token = blockIdx.x * 4 + wv;
  const int branch = blockIdx.y;
  const int dil = branch + 1;
  const int xx = token % 56;
  const int yy = (token / 56) % 56;
  const int bimg = token / 3136;
  const float scale = 0.17677669529663687f;  // 1/sqrt(32)
  const int cb = branch * 128;

  const _Float16* qrow = qkv + (size_t)token * ROWQKV;
  const float q0 = (float)qrow[cb + lane];
  const float q1 = (float)qrow[cb + 64 + lane];

  float l0[9], l1[9], v0[9], v1[9];
#pragma unroll
  for (int j = 0; j < 9; ++j) {
    const int ny = yy + (j / 3 - 1) * dil;
    const int nx = xx + (j % 3 - 1) * dil;
    float k0 = 0.f, k1 = 0.f, vv0 = 0.f, vv1 = 0.f;
    if ((unsigned)ny < 56u && (unsigned)nx < 56u) {
      const _Float16* nrow = qkv + ((size_t)(bimg * 3136 + ny * 56 + nx)) * ROWQKV;
      k0 = (float)nrow[384 + cb + lane];
      k1 = (float)nrow[384 + cb + 64 + lane];
      vv0 = (float)nrow[768 + cb + lane];
      vv1 = (float)nrow[768 + cb + 64 + lane];
    }
    float p0 = q0 * k0, p1 = q1 * k1;
#pragma unroll
    for (int s = 1; s < 32; s <<= 1) {
      p0 += __shfl_xor(p0, s, 64);
      p1 += __shfl_xor(p1, s, 64);
    }
    l0[j] = p0 * scale;
    l1[j] = p1 * scale;
    v0[j] = vv0;
    v1[j] = vv1;
  }

  float m0 = l0[0], m1 = l1[0];
#pragma unroll
  for (int j = 1; j < 9; ++j) { m0 = fmaxf(m0, l0[j]); m1 = fmaxf(m1, l1[j]); }
  float s0 = 0.f, s1 = 0.f;
#pragma unroll
  for (int j = 0; j < 9; ++j) {
    l0[j] = expf(l0[j] - m0); s0 += l0[j];
    l1[j] = expf(l1[j] - m1); s1 += l1[j];
  }
  const float r0 = 1.f / s0, r1 = 1.f / s1;
  float o0 = 0.f, o1 = 0.f;
#pragma unroll
  for (int j = 0; j < 9; ++j) { o0 = fmaf(l0[j], v0[j], o0); o1 = fmaf(l1[j], v1[j], o1); }

  _Float16* yrow = y + (size_t)token * CDIM + cb;
  yrow[lane] = (_Float16)(o0 * r0);
  yrow[64 + lane] = (_Float16)(o1 * r1);
}

extern "C" void kernel_launch(void* const* d_in, const int* in_sizes, int n_in,
                              void* d_out, int out_size, void* d_ws, size_t ws_size,
                              hipStream_t stream) {
  const float* x = (const float*)d_in[0];       // [16,56,56,384]
  const float* w_qkv = (const float*)d_in[1];   // [1152,384]
  const float* w_proj = (const float*)d_in[2];  // [384,384]
  const float* b_proj = (const float*)d_in[3];  // [384]
  float* out = (float*)d_out;                   // [50176,384]

  _Float16* xh = (_Float16*)d_ws;                     // 50176*384
  _Float16* wqh = xh + (size_t)NTOK * CDIM;           // 1152*384
  _Float16* wph = wqh + (size_t)ROWQKV * CDIM;        // 384*384
  _Float16* qkvh = wph + (size_t)CDIM * CDIM;         // 50176*1152
  _Float16* yh = qkvh + (size_t)NTOK * ROWQKV;        // 50176*384

  conv_f32_f16<<<2048, 256, 0, stream>>>(x, xh, NTOK * CDIM / 4);
  conv_f32_f16<<<64, 256, 0, stream>>>(w_qkv, wqh, ROWQKV * CDIM / 4);
  conv_f32_f16<<<64, 256, 0, stream>>>(w_proj, wph, CDIM * CDIM / 4);

  gemm_f16<true><<<dim3(NTOK / 128, ROWQKV / 128), 256, 0, stream>>>(
      xh, wqh, nullptr, qkvh, ROWQKV, CDIM);

  attn_kernel<<<dim3(NTOK / 4, 3), 256, 0, stream>>>(qkvh, yh);

  gemm_f16<false><<<dim3(NTOK / 128, CDIM / 128), 256, 0, stream>>>(
      yh, wph, b_proj, out, CDIM, CDIM);
}

// Round 3
// 208.754 us; speedup vs baseline: 4.5258x; 1.5112x over previous
//
#include <hip/hip_runtime.h>
#include <hip/hip_bf16.h>

// MultiDilatelocalAttention, round 3: per-(token,head)-thread attention with
// v_dot2_f32_f16 in-thread reductions (no cross-lane ops). GEMMs unchanged.

#define NTOK 50176
#define ROWQKV 1152
#define CDIM 384

typedef _Float16 half2v __attribute__((ext_vector_type(2)));
typedef _Float16 half8 __attribute__((ext_vector_type(8)));
typedef float floatx4 __attribute__((ext_vector_type(4)));

typedef __attribute__((address_space(1))) const unsigned int GU32;
typedef __attribute__((address_space(3))) unsigned int LU32;

// ---------------- fp32 -> fp16 conversion ----------------
__global__ __launch_bounds__(256) void conv_f32_f16(const float* __restrict__ in,
                                                    _Float16* __restrict__ out, int n4) {
  int i = blockIdx.x * 256 + threadIdx.x;
  const int stride = gridDim.x * 256;
  for (; i < n4; i += stride) {
    float4 v = ((const float4*)in)[i];
    union { _Float16 h[4]; uint2 u; } o;
    o.h[0] = (_Float16)v.x; o.h[1] = (_Float16)v.y;
    o.h[2] = (_Float16)v.z; o.h[3] = (_Float16)v.w;
    ((uint2*)out)[i] = o.u;
  }
}

// ---------------- f16 MFMA GEMM: C[M][N] = A[M][K] * B[N][K]^T ----------------
template <bool HALF_OUT>
__global__ __launch_bounds__(256) void gemm_f16(const _Float16* __restrict__ A,
                                                const _Float16* __restrict__ B,
                                                const float* __restrict__ bias,
                                                void* __restrict__ Cout,
                                                int N, int K) {
  __shared__ _Float16 As[128 * 32];
  __shared__ _Float16 Bs[128 * 32];
  const int tid = threadIdx.x;
  const int lane = tid & 63;
  const int wv = tid >> 6;
  const int wr = wv >> 1, wc = wv & 1;
  const size_t row0 = (size_t)blockIdx.x * 128;
  const int col0 = blockIdx.y * 128;

  const int srow = tid >> 2;
  const int sslot = tid & 3;
  const int gslot = sslot ^ ((srow >> 1) & 3);
  const _Float16* Abase = A + (row0 + srow) * (size_t)K + gslot * 8;
  const _Float16* Bbase = B + ((size_t)(col0 + srow)) * (size_t)K + gslot * 8;
  char* AsB = (char*)As;
  char* BsB = (char*)Bs;

  const int fr = lane & 15;
  const int fq = lane >> 4;
  const int rpos = (fq ^ ((fr >> 1) & 3)) * 8;

  floatx4 acc[4][4];
#pragma unroll
  for (int i = 0; i < 4; ++i)
#pragma unroll
    for (int j = 0; j < 4; ++j) acc[i][j] = (floatx4){0.f, 0.f, 0.f, 0.f};

  for (int k0 = 0; k0 < K; k0 += 32) {
    __builtin_amdgcn_global_load_lds((GU32*)(Abase + k0), (LU32*)(AsB + tid * 16), 16, 0, 0);
    __builtin_amdgcn_global_load_lds((GU32*)(Abase + (size_t)64 * K + k0),
                                     (LU32*)(AsB + tid * 16 + 4096), 16, 0, 0);
    __builtin_amdgcn_global_load_lds((GU32*)(Bbase + k0), (LU32*)(BsB + tid * 16), 16, 0, 0);
    __builtin_amdgcn_global_load_lds((GU32*)(Bbase + (size_t)64 * K + k0),
                                     (LU32*)(BsB + tid * 16 + 4096), 16, 0, 0);
    __syncthreads();
    half8 af[4], bf[4];
#pragma unroll
    for (int f = 0; f < 4; ++f) {
      af[f] = *(const half8*)&As[(wr * 64 + f * 16 + fr) * 32 + rpos];
      bf[f] = *(const half8*)&Bs[(wc * 64 + f * 16 + fr) * 32 + rpos];
    }
#pragma unroll
    for (int i = 0; i < 4; ++i)
#pragma unroll
      for (int j = 0; j < 4; ++j)
        acc[i][j] = __builtin_amdgcn_mfma_f32_16x16x32_f16(af[i], bf[j], acc[i][j], 0, 0, 0);
    __syncthreads();
  }

  const int crow = wr * 64 + (lane >> 4) * 4;
  const int ccol = wc * 64 + (lane & 15);
#pragma unroll
  for (int fm = 0; fm < 4; ++fm) {
#pragma unroll
    for (int fn = 0; fn < 4; ++fn) {
      const size_t r0 = (row0 + crow + fm * 16) * (size_t)N + col0 + ccol + fn * 16;
      if (HALF_OUT) {
        _Float16* C = (_Float16*)Cout;
#pragma unroll
        for (int j = 0; j < 4; ++j) C[r0 + (size_t)j * N] = (_Float16)acc[fm][fn][j];
      } else {
        float* C = (float*)Cout;
        const float bz = bias[col0 + ccol + fn * 16];
#pragma unroll
        for (int j = 0; j < 4; ++j) C[r0 + (size_t)j * N] = acc[fm][fn][j] + bz;
      }
    }
  }
}

// ---------------- Local attention: one thread per (token, head) ----------------
// Thread owns d=32 head slice: q in regs, per-tap k dot via v_dot2_f32_f16,
// softmax over 9 in regs, second tap pass accumulates out[32] in fp32.
__global__ __launch_bounds__(256) void attn_kernel(const _Float16* __restrict__ qkv,
                                                   _Float16* __restrict__ y) {
  const int idx = blockIdx.x * 256 + threadIdx.x;  // token*12 + head
  const int head = idx % 12;
  const int token = idx / 12;
  const int branch = head >> 2;
  const int dil = branch + 1;
  const int cbase = branch * 128 + (head & 3) * 32;
  const int xx = token % 56;
  const int yy = (token / 56) % 56;
  const int bimg = token / 3136;
  const float scale = 0.17677669529663687f;  // 1/sqrt(32)

  const _Float16* qp = qkv + (size_t)token * ROWQKV + cbase;
  half2v qh[16];
  *(half8*)&qh[0] = *(const half8*)(qp);
  *(half8*)&qh[4] = *(const half8*)(qp + 8);
  *(half8*)&qh[8] = *(const half8*)(qp + 16);
  *(half8*)&qh[12] = *(const half8*)(qp + 24);

  const size_t nbase = (size_t)bimg * 3136;

  // pass 1: logits
  float l[9];
#pragma unroll
  for (int j = 0; j < 9; ++j) {
    const int ny = yy + (j / 3 - 1) * dil;
    const int nx = xx + (j % 3 - 1) * dil;
    float d = 0.f;
    if ((unsigned)ny < 56u && (unsigned)nx < 56u) {
      const _Float16* kp = qkv + (nbase + ny * 56 + nx) * ROWQKV + 384 + cbase;
      half2v kh[16];
      *(half8*)&kh[0] = *(const half8*)(kp);
      *(half8*)&kh[4] = *(const half8*)(kp + 8);
      *(half8*)&kh[8] = *(const half8*)(kp + 16);
      *(half8*)&kh[12] = *(const half8*)(kp + 24);
#if __has_builtin(__builtin_amdgcn_fdot2)
#pragma unroll
      for (int c = 0; c < 16; ++c) d = __builtin_amdgcn_fdot2(qh[c], kh[c], d, false);
#else
#pragma unroll
      for (int c = 0; c < 16; ++c)
        d += (float)qh[c][0] * (float)kh[c][0] + (float)qh[c][1] * (float)kh[c][1];
#endif
    }
    l[j] = d * scale;
  }

  // softmax over 9 (OOB taps contribute logit 0, matching reference zero-pad)
  float m = l[0];
#pragma unroll
  for (int j = 1; j < 9; ++j) m = fmaxf(m, l[j]);
  float s = 0.f;
#pragma unroll
  for (int j = 0; j < 9; ++j) { l[j] = expf(l[j] - m); s += l[j]; }
  const float rs = 1.f / s;

  // pass 2: out += p[j] * v
  float out[32];
#pragma unroll
  for (int c = 0; c < 32; ++c) out[c] = 0.f;
#pragma unroll
  for (int j = 0; j < 9; ++j) {
    const int ny = yy + (j / 3 - 1) * dil;
    const int nx = xx + (j % 3 - 1) * dil;
    if ((unsigned)ny < 56u && (unsigned)nx < 56u) {
      const _Float16* vp = qkv + (nbase + ny * 56 + nx) * ROWQKV + 768 + cbase;
      half8 vh[4];
      vh[0] = *(const half8*)(vp);
      vh[1] = *(const half8*)(vp + 8);
      vh[2] = *(const half8*)(vp + 16);
      vh[3] = *(const half8*)(vp + 24);
      const float p = l[j];
#pragma unroll
      for (int g = 0; g < 4; ++g)
#pragma unroll
        for (int e = 0; e < 8; ++e) out[g * 8 + e] = fmaf(p, (float)vh[g][e], out[g * 8 + e]);
    }
  }

  _Float16* yp = y + (size_t)token * CDIM + cbase;
  half8 oh[4];
#pragma unroll
  for (int g = 0; g < 4; ++g) {
#pragma unroll
    for (int e = 0; e < 8; ++e) oh[g][e] = (_Float16)(out[g * 8 + e] * rs);
    *(half8*)(yp + g * 8) = oh[g];
  }
}

extern "C" void kernel_launch(void* const* d_in, const int* in_sizes, int n_in,
                              void* d_out, int out_size, void* d_ws, size_t ws_size,
                              hipStream_t stream) {
  const float* x = (const float*)d_in[0];       // [16,56,56,384]
  const float* w_qkv = (const float*)d_in[1];   // [1152,384]
  const float* w_proj = (const float*)d_in[2];  // [384,384]
  const float* b_proj = (const float*)d_in[3];  // [384]
  float* out = (float*)d_out;                   // [50176,384]

  _Float16* xh = (_Float16*)d_ws;                     // 50176*384
  _Float16* wqh = xh + (size_t)NTOK * CDIM;           // 1152*384
  _Float16* wph = wqh + (size_t)ROWQKV * CDIM;        // 384*384
  _Float16* qkvh = wph + (size_t)CDIM * CDIM;         // 50176*1152
  _Float16* yh = qkvh + (size_t)NTOK * ROWQKV;        // 50176*384

  conv_f32_f16<<<2048, 256, 0, stream>>>(x, xh, NTOK * CDIM / 4);
  conv_f32_f16<<<64, 256, 0, stream>>>(w_qkv, wqh, ROWQKV * CDIM / 4);
  conv_f32_f16<<<64, 256, 0, stream>>>(w_proj, wph, CDIM * CDIM / 4);

  gemm_f16<true><<<dim3(NTOK / 128, ROWQKV / 128), 256, 0, stream>>>(
      xh, wqh, nullptr, qkvh, ROWQKV, CDIM);

  attn_kernel<<<(NTOK * 12) / 256, 256, 0, stream>>>(qkvh, yh);

  gemm_f16<false><<<dim3(NTOK / 128, CDIM / 128), 256, 0, stream>>>(
      yh, wph, b_proj, out, CDIM, CDIM);
}